// Round 7
// baseline (5632.792 us; speedup 1.0000x reference)
//
#include <hip/hip_runtime.h>
#include <math.h>

#define NPTS    32768
#define NPOINT  2048
#define NSAMPLE 32
#define RADIUS2 0.25f
#define D_IN    64
#define D0      67
#define H1DIM   64
#define H2DIM   128

// ---------------------------------------------------------------------------
// Kernel A: multi-CU FPS + heaters -- R0 proven structure + coords-in-slot.
// History: R0 fabric sync = 2.17us/iter (4.44ms, proven). Single-CU =
// 3.1us/iter invariant to all knobs (R11-R14). sc0 L2-local sync: falsified
// (R5 fail, R6 fallback) -- agent-scope fabric RT is unavoidable.
// R16: shave R0's critical path. (a) COORDS-IN-SLOT: publish candidate
// (x,y,z) in the slot as three TAGGED u64 words (each 8B word carries the
// 16-bit iteration tag -> out-of-order arrival of the 3 relaxed stores can
// never produce a torn accept; same tag-accept safety as R0). The dependent
// far-coords fetch (xyz[3w..], ~200-400cy L2 hit AFTER the reduce) leaves
// the critical path; winner coords come from ballot+shfl broadcast.
// Candidate coords are captured inside the existing unrolled rescan (no
// dynamic register indexing). (b) spin depth 4 -> 6: sample cadence RT/4 ->
// RT/6. Everything else (heater co-residency, no LDS blocker, 32x64 fps
// roles, parity banks, 128B slots, u64 max == np.argmax first-occurrence,
// poison never matches tags) is R0 verbatim.
// Exact numerics: op order sub,mul,mul,add,mul,add,fminf under contract(off);
// coords round-trip as raw bits (exact).
// ---------------------------------------------------------------------------
#define FPB  32     // fps blocks
#define FBT  64     // active fps threads per block (one wave)
#define FPP  16     // points per thread; FPB*FBT*FPP == NPTS
#define SPAD 16     // u64s per slot (128 B line)
#define HEAT_DONE 0x600DD00Du
#define HEAT_CAP  4096      // outer-loop safety cap (~50ms)

__global__ __launch_bounds__(256) void fps_heat_kernel(const float* __restrict__ xyz,
                                                       float* __restrict__ d_out,
                                                       unsigned long long* __restrict__ slots,
                                                       unsigned int* __restrict__ flag,
                                                       float* __restrict__ hdump)
{
#pragma clang fp contract(off)
    const int t = threadIdx.x;
    const int b = blockIdx.x;

    if (b >= FPB) {
        // ----------------- HEATER: dense FMA, poll flag every ~13us --------
        float a0 = 1.0f + (float)(b * 256 + t) * 1e-6f;
        float a1 = a0 + 0.1f, a2 = a0 + 0.2f, a3 = a0 + 0.3f;
        float a4 = a0 + 0.4f, a5 = a0 + 0.5f, a6 = a0 + 0.6f, a7 = a0 + 0.7f;
        for (int outer = 0; outer < HEAT_CAP; ++outer) {
            #pragma unroll 8
            for (int n = 0; n < 2048; ++n) {
                a0 = fmaf(a0, 0.9999999f, 1e-7f);
                a1 = fmaf(a1, 0.9999999f, 1e-7f);
                a2 = fmaf(a2, 0.9999999f, 1e-7f);
                a3 = fmaf(a3, 0.9999999f, 1e-7f);
                a4 = fmaf(a4, 0.9999999f, 1e-7f);
                a5 = fmaf(a5, 0.9999999f, 1e-7f);
                a6 = fmaf(a6, 0.9999999f, 1e-7f);
                a7 = fmaf(a7, 0.9999999f, 1e-7f);
            }
            if (__hip_atomic_load(flag, __ATOMIC_RELAXED,
                                  __HIP_MEMORY_SCOPE_AGENT) == HEAT_DONE)
                break;
        }
        // never-true guard store keeps the loop from being optimized out
        float s = a0 + a1 + a2 + a3 + a4 + a5 + a6 + a7;
        if (s == 1234.56789f) hdump[(b - FPB) * 256 + t] = s;
        return;
    }

    if (t >= FBT) return;   // fps role: one wave per block

    const int base = b * (FBT * FPP);

    float X[FPP], Y[FPP], Z[FPP], D[FPP];
    #pragma unroll
    for (int k = 0; k < FPP; ++k) {
        const int p = base + k * FBT + t;
        X[k] = xyz[3 * p + 0];
        Y[k] = xyz[3 * p + 1];
        Z[k] = xyz[3 * p + 2];
        D[k] = 1e38f;
    }
    float fx = xyz[0], fy = xyz[1], fz = xyz[2];   // far = 0 at start

    for (int i = 0; i < NPOINT; ++i) {
        const int par = i & 1;
        const unsigned tag = (unsigned)(i + 1);

        if (b == 0 && t == 0) {   // emit current far point's coords
            d_out[3 * i + 0] = fx;
            d_out[3 * i + 1] = fy;
            d_out[3 * i + 2] = fz;
        }

        // --- distance update (exact np op order) + thread max (4 accs) ---
        float m0 = -1.0f, m1 = -1.0f, m2 = -1.0f, m3 = -1.0f;
        #pragma unroll
        for (int k = 0; k < FPP; k += 4) {
            {   float dx = X[k+0]-fx, dy = Y[k+0]-fy, dz = Z[k+0]-fz;
                float d = ((dx*dx)+(dy*dy))+(dz*dz);
                float Dn = fminf(D[k+0], d); D[k+0] = Dn; m0 = fmaxf(m0, Dn); }
            {   float dx = X[k+1]-fx, dy = Y[k+1]-fy, dz = Z[k+1]-fz;
                float d = ((dx*dx)+(dy*dy))+(dz*dz);
                float Dn = fminf(D[k+1], d); D[k+1] = Dn; m1 = fmaxf(m1, Dn); }
            {   float dx = X[k+2]-fx, dy = Y[k+2]-fy, dz = Z[k+2]-fz;
                float d = ((dx*dx)+(dy*dy))+(dz*dz);
                float Dn = fminf(D[k+2], d); D[k+2] = Dn; m2 = fmaxf(m2, Dn); }
            {   float dx = X[k+3]-fx, dy = Y[k+3]-fy, dz = Z[k+3]-fz;
                float d = ((dx*dx)+(dy*dy))+(dz*dz);
                float Dn = fminf(D[k+3], d); D[k+3] = Dn; m3 = fmaxf(m3, Dn); }
        }
        const float m = fmaxf(fmaxf(m0, m1), fmaxf(m2, m3));

        // --- wave max (butterfly -> all lanes) ---
        float wmax = m;
        #pragma unroll
        for (int mask = 32; mask >= 1; mask >>= 1)
            wmax = fmaxf(wmax, __shfl_xor(wmax, mask, 64));

        // --- block winner: equality rescan + wave min; capture coords -----
        int   cand = 0x7fffffff;
        float ccx = 0.0f, ccy = 0.0f, ccz = 0.0f;
        if (m == wmax) {
            #pragma unroll
            for (int k = FPP - 1; k >= 0; --k)
                if (D[k] == wmax) {                   // lowest k wins
                    cand = base + k * FBT + t;
                    ccx = X[k]; ccy = Y[k]; ccz = Z[k];
                }
        }
        int wcand = cand;
        #pragma unroll
        for (int mask = 32; mask >= 1; mask >>= 1)
            wcand = min(wcand, __shfl_xor(wcand, mask, 64));

        // owner lane broadcasts its candidate's coords to the wave
        {
            unsigned long long ball = __ballot(cand == wcand);
            int src = __ffsll(ball) - 1;
            ccx = __shfl(ccx, src, 64);
            ccy = __shfl(ccy, src, 64);
            ccz = __shfl(ccz, src, 64);
        }

        // --- publish: 3 tagged u64 words in own 128B slot ------------------
        if (t == 0) {
            const unsigned db  = __float_as_uint(wmax);       // d>=0: order-preserving
            const unsigned inv = 0xFFFFu - (unsigned)wcand;   // bigger = smaller idx
            const unsigned xb  = __float_as_uint(ccx);
            const unsigned yb  = __float_as_uint(ccy);
            const unsigned zb  = __float_as_uint(ccz);
            unsigned long long s0 = ((unsigned long long)db << 32)
                                  | ((unsigned long long)inv << 16)
                                  | (unsigned long long)tag;
            unsigned long long s1 = ((unsigned long long)xb << 32)
                                  | ((unsigned long long)(yb >> 16) << 16)
                                  | (unsigned long long)tag;
            unsigned long long s2 = ((unsigned long long)zb << 32)
                                  | ((unsigned long long)(yb & 0xFFFFu) << 16)
                                  | (unsigned long long)tag;
            unsigned long long* fp = &slots[(size_t)(par * FPB + b) * SPAD];
            __hip_atomic_store(fp + 0, s0, __ATOMIC_RELAXED,
                               __HIP_MEMORY_SCOPE_AGENT);
            __hip_atomic_store(fp + 1, s1, __ATOMIC_RELAXED,
                               __HIP_MEMORY_SCOPE_AGENT);
            __hip_atomic_store(fp + 2, s2, __ATOMIC_RELAXED,
                               __HIP_MEMORY_SCOPE_AGENT);
        }

        // --- pipelined 6-deep rotating spin, 3 tagged words per sample -----
        unsigned long long va, vb, vc;
        {
            const unsigned long long* sp =
                &slots[(size_t)(par * FPB + (t & 31)) * SPAD];
#define LD3(A, B, C)                                                         \
            do {                                                             \
                A = __hip_atomic_load(sp + 0, __ATOMIC_RELAXED,              \
                                      __HIP_MEMORY_SCOPE_AGENT);             \
                B = __hip_atomic_load(sp + 1, __ATOMIC_RELAXED,              \
                                      __HIP_MEMORY_SCOPE_AGENT);             \
                C = __hip_atomic_load(sp + 2, __ATOMIC_RELAXED,              \
                                      __HIP_MEMORY_SCOPE_AGENT);             \
            } while (0)
#define FRESH(A, B, C)                                                       \
            ((unsigned)((A) & 0xFFFFull) == tag &&                           \
             (unsigned)((B) & 0xFFFFull) == tag &&                           \
             (unsigned)((C) & 0xFFFFull) == tag)
            unsigned long long w0a, w0b, w0c, w1a, w1b, w1c, w2a, w2b, w2c;
            unsigned long long w3a, w3b, w3c, w4a, w4b, w4c, w5a, w5b, w5c;
            LD3(w0a, w0b, w0c); LD3(w1a, w1b, w1c); LD3(w2a, w2b, w2c);
            LD3(w3a, w3b, w3c); LD3(w4a, w4b, w4c); LD3(w5a, w5b, w5c);
            for (;;) {
                if (FRESH(w0a, w0b, w0c)) { va = w0a; vb = w0b; vc = w0c; break; }
                LD3(w0a, w0b, w0c);
                if (FRESH(w1a, w1b, w1c)) { va = w1a; vb = w1b; vc = w1c; break; }
                LD3(w1a, w1b, w1c);
                if (FRESH(w2a, w2b, w2c)) { va = w2a; vb = w2b; vc = w2c; break; }
                LD3(w2a, w2b, w2c);
                if (FRESH(w3a, w3b, w3c)) { va = w3a; vb = w3b; vc = w3c; break; }
                LD3(w3a, w3b, w3c);
                if (FRESH(w4a, w4b, w4c)) { va = w4a; vb = w4b; vc = w4c; break; }
                LD3(w4a, w4b, w4c);
                if (FRESH(w5a, w5b, w5c)) { va = w5a; vb = w5b; vc = w5c; break; }
                LD3(w5a, w5b, w5c);
            }
#undef LD3
#undef FRESH
        }

        // --- global winner: u64 butterfly max on (d|inv|tag) ---------------
        unsigned long long vmax = va;
        #pragma unroll
        for (int mask = 32; mask >= 1; mask >>= 1) {
            unsigned long long o = __shfl_xor(vmax, mask, 64);
            if (o > vmax) vmax = o;
        }

        // winner's coords from the lane holding the winning slot
        {
            float xr = __uint_as_float((unsigned)(vb >> 32));
            float zr = __uint_as_float((unsigned)(vc >> 32));
            unsigned yr = (((unsigned)(vb >> 16) & 0xFFFFu) << 16)
                        |  ((unsigned)(vc >> 16) & 0xFFFFu);
            float yf = __uint_as_float(yr);
            unsigned long long ball = __ballot(va == vmax);
            int src = __ffsll(ball) - 1;
            fx = __shfl(xr, src, 64);
            fy = __shfl(yf, src, 64);
            fz = __shfl(zr, src, 64);
        }
    }

    if (b == 0 && t == 0)   // release the heaters
        __hip_atomic_store(flag, HEAT_DONE, __ATOMIC_RELAXED,
                           __HIP_MEMORY_SCOPE_AGENT);
}

// ---------------------------------------------------------------------------
// Kernel B: ball query — exact (d2, idx)-lexicographic 32-smallest per centroid
// ---------------------------------------------------------------------------
#define BT   256
#define BCAP 3072   // in-radius cap (expected worst ~1100 near origin)

__global__ __launch_bounds__(BT) void ballq_kernel(const float* __restrict__ xyz,
                                                   const float* __restrict__ newxyz,
                                                   int* __restrict__ gidx)
{
#pragma clang fp contract(off)
    __shared__ float Ld[BCAP + 128];
    __shared__ int   Li[BCAP + 128];
    __shared__ int   cnt, pcnt;
    __shared__ float cs[3];
    __shared__ float rv[BT / 64];
    __shared__ int   ri[BT / 64], rj[BT / 64];

    const int m = blockIdx.x;
    const int t = threadIdx.x;

    if (t == 0) {
        cnt = 0; pcnt = 0;
        cs[0] = newxyz[3 * m + 0];
        cs[1] = newxyz[3 * m + 1];
        cs[2] = newxyz[3 * m + 2];
    }
    __syncthreads();
    const float cx = cs[0], cy = cs[1], cz = cs[2];

    for (int p = t; p < NPTS; p += BT) {
        float dx = cx - xyz[3 * p + 0];
        float dy = cy - xyz[3 * p + 1];
        float dz = cz - xyz[3 * p + 2];
        float d2 = ((dx * dx) + (dy * dy)) + (dz * dz);
        if (!(d2 > RADIUS2)) {                    // in radius (keeps d2 == r^2)
            int pos = atomicAdd(&cnt, 1);
            if (pos < BCAP) { Ld[pos] = d2; Li[pos] = p; }
        } else if (p < 128) {                     // padding candidates (masked 1e9)
            int pos = atomicAdd(&pcnt, 1);
            Ld[BCAP + pos] = 1e9f;
            Li[BCAP + pos] = p;
        }
    }
    __syncthreads();

    const int L = (cnt < BCAP) ? cnt : BCAP;
    const int P = pcnt;
    if (t < P) {  // compact pads to follow the in-radius list
        float d = Ld[BCAP + t];
        int   x = Li[BCAP + t];
        Ld[L + t] = d;
        Li[L + t] = x;
    }
    __syncthreads();
    const int M = L + P;

    for (int r = 0; r < NSAMPLE; ++r) {
        float bd = 3e38f;
        int   bi = 0x7fffffff;
        int   bj = 0;
        for (int j = t; j < M; j += BT) {
            float d = Ld[j];
            int   x = Li[j];
            if (d < bd || (d == bd && x < bi)) { bd = d; bi = x; bj = j; }
        }
        #pragma unroll
        for (int mask = 32; mask >= 1; mask >>= 1) {
            float ov = __shfl_xor(bd, mask, 64);
            int   oi = __shfl_xor(bi, mask, 64);
            int   oj = __shfl_xor(bj, mask, 64);
            if (ov < bd || (ov == bd && oi < bi)) { bd = ov; bi = oi; bj = oj; }
        }
        if ((t & 63) == 0) { rv[t >> 6] = bd; ri[t >> 6] = bi; rj[t >> 6] = bj; }
        __syncthreads();
        if (t == 0) {
            float v0 = rv[0]; int i0 = ri[0]; int j0 = rj[0];
            for (int w = 1; w < BT / 64; ++w) {
                if (rv[w] < v0 || (rv[w] == v0 && ri[w] < i0)) { v0 = rv[w]; i0 = ri[w]; j0 = rj[w]; }
            }
            gidx[m * NSAMPLE + r] = i0;
            Ld[j0] = 3e38f;   // remove from candidate set
        }
        __syncthreads();
    }
}

// ---------------------------------------------------------------------------
// Kernel C: gather -> MLP(67->64->128, exact GELU) -> maxpool, 1 block/centroid
// ---------------------------------------------------------------------------
__global__ __launch_bounds__(256) void mlp_kernel(const float* __restrict__ xyz,
                                                  const float* __restrict__ feat,
                                                  const float* __restrict__ W1,
                                                  const float* __restrict__ b1,
                                                  const float* __restrict__ W2,
                                                  const float* __restrict__ b2,
                                                  const float* __restrict__ newxyz,
                                                  const int* __restrict__ gidx,
                                                  float* __restrict__ out_pooled)
{
    __shared__ float W1s[D0 * H1DIM];            // 17152 B
    __shared__ float W2s[H1DIM * H2DIM];         // 32768 B
    __shared__ float b1s[H1DIM];
    __shared__ float b2s[H2DIM];
    __shared__ float Xs[NSAMPLE][D0 + 1];        // 68 stride
    __shared__ float H1s[NSAMPLE][H1DIM + 4];    // 68 stride
    __shared__ float H2s[NSAMPLE][H2DIM + 4];    // 132 stride
    __shared__ int   idxs[NSAMPLE];
    __shared__ float cs[3];

    const int m = blockIdx.x;
    const int t = threadIdx.x;

    for (int i = t; i < D0 * H1DIM; i += 256) W1s[i] = W1[i];
    for (int i = t; i < H1DIM * H2DIM; i += 256) W2s[i] = W2[i];
    if (t < H1DIM) b1s[t] = b1[t];
    if (t < H2DIM) b2s[t] = b2[t];
    if (t < NSAMPLE) idxs[t] = gidx[m * NSAMPLE + t];
    if (t < 3) cs[t] = newxyz[3 * m + t];
    __syncthreads();

    const int s  = t >> 3;   // sample 0..31
    const int u  = t & 7;    // sub-worker 0..7

    {   // gather: g_xyz (relative) + feat
        const int id = idxs[s];
        const float4* f4 = (const float4*)(feat + (size_t)id * D_IN);
        float4 a = f4[u * 2 + 0];
        float4 b = f4[u * 2 + 1];
        Xs[s][3 + u * 8 + 0] = a.x; Xs[s][3 + u * 8 + 1] = a.y;
        Xs[s][3 + u * 8 + 2] = a.z; Xs[s][3 + u * 8 + 3] = a.w;
        Xs[s][3 + u * 8 + 4] = b.x; Xs[s][3 + u * 8 + 5] = b.y;
        Xs[s][3 + u * 8 + 6] = b.z; Xs[s][3 + u * 8 + 7] = b.w;
        if (u == 0) {
            Xs[s][0] = xyz[3 * id + 0] - cs[0];
            Xs[s][1] = xyz[3 * id + 1] - cs[1];
            Xs[s][2] = xyz[3 * id + 2] - cs[2];
        }
    }
    __syncthreads();

    // layer 1: each thread computes 8 of 64 outputs for its sample
    {
        float acc[8];
        #pragma unroll
        for (int v = 0; v < 8; ++v) acc[v] = b1s[u * 8 + v];
        for (int k = 0; k < D0; ++k) {
            float xk = Xs[s][k];
            float4 wa = *(const float4*)&W1s[k * H1DIM + u * 8 + 0];
            float4 wb = *(const float4*)&W1s[k * H1DIM + u * 8 + 4];
            acc[0] = fmaf(xk, wa.x, acc[0]); acc[1] = fmaf(xk, wa.y, acc[1]);
            acc[2] = fmaf(xk, wa.z, acc[2]); acc[3] = fmaf(xk, wa.w, acc[3]);
            acc[4] = fmaf(xk, wb.x, acc[4]); acc[5] = fmaf(xk, wb.y, acc[5]);
            acc[6] = fmaf(xk, wb.z, acc[6]); acc[7] = fmaf(xk, wb.w, acc[7]);
        }
        #pragma unroll
        for (int v = 0; v < 8; ++v) {
            float a = acc[v];
            H1s[s][u * 8 + v] = 0.5f * a * (1.0f + erff(a * 0.70710678118654752f));
        }
    }
    __syncthreads();

    // layer 2: each thread computes 16 of 128 outputs for its sample
    {
        float acc[16];
        #pragma unroll
        for (int v = 0; v < 16; ++v) acc[v] = b2s[u * 16 + v];
        for (int k = 0; k < H1DIM; ++k) {
            float hk = H1s[s][k];
            #pragma unroll
            for (int q = 0; q < 4; ++q) {
                float4 w = *(const float4*)&W2s[k * H2DIM + u * 16 + q * 4];
                acc[q * 4 + 0] = fmaf(hk, w.x, acc[q * 4 + 0]);
                acc[q * 4 + 1] = fmaf(hk, w.y, acc[q * 4 + 1]);
                acc[q * 4 + 2] = fmaf(hk, w.z, acc[q * 4 + 2]);
                acc[q * 4 + 3] = fmaf(hk, w.w, acc[q * 4 + 3]);
            }
        }
        #pragma unroll
        for (int v = 0; v < 16; ++v) {
            float a = acc[v];
            H2s[s][u * 16 + v] = 0.5f * a * (1.0f + erff(a * 0.70710678118654752f));
        }
    }
    __syncthreads();

    // maxpool over 32 samples
    if (t < H2DIM) {
        float mx = H2s[0][t];
        #pragma unroll 4
        for (int ss = 1; ss < NSAMPLE; ++ss) mx = fmaxf(mx, H2s[ss][t]);
        out_pooled[(size_t)m * H2DIM + t] = mx;
    }
}

// ---------------------------------------------------------------------------
extern "C" void kernel_launch(void* const* d_in, const int* in_sizes, int n_in,
                              void* d_out, int out_size, void* d_ws, size_t ws_size,
                              hipStream_t stream) {
    const float* xyz  = (const float*)d_in[0];
    const float* feat = (const float*)d_in[1];
    const float* W1   = (const float*)d_in[2];
    const float* b1   = (const float*)d_in[3];
    const float* W2   = (const float*)d_in[4];
    const float* b2   = (const float*)d_in[5];
    float* out = (float*)d_out;
    int*   gidx = (int*)d_ws;                               // 256 KiB
    unsigned int* flag = (unsigned int*)((char*)d_ws + NPOINT * NSAMPLE * 4);
    // ws poison 0xAAAAAAAA != HEAT_DONE -> heater armed each call.

    // Cross-block slots + heater guard dump: pooled-output region (unused
    // until mlp overwrites). Slots: 2 banks x 32 x 128B = 8KB; dump at +16KB.
    unsigned long long* slots = (unsigned long long*)(out + 3 * NPOINT);
    float* hdump = out + 3 * NPOINT + 4096;

    fps_heat_kernel<<<256, 256, 0, stream>>>(xyz, out, slots, flag, hdump);
    ballq_kernel<<<NPOINT, BT, 0, stream>>>(xyz, out, gidx);
    mlp_kernel<<<NPOINT, 256, 0, stream>>>(xyz, feat, W1, b1, W2, b2,
                                           out, gidx, out + 3 * NPOINT);
}

// Round 8
// 4917.411 us; speedup vs baseline: 1.1455x; 1.1455x over previous
//
#include <hip/hip_runtime.h>
#include <math.h>

#define NPTS    32768
#define NPOINT  2048
#define NSAMPLE 32
#define RADIUS2 0.25f
#define D_IN    64
#define D0      67
#define H1DIM   64
#define H2DIM   128

// ---------------------------------------------------------------------------
// Kernel A: multi-CU FPS + heaters -- R0 proven structure + MONOTONE EARLY
// EXIT on the cross-block wait.
// History: R0 fabric sync = 2.17us/iter (4.41ms, proven best). Single-CU =
// 3.1us/iter invariant to all knobs (R11-R14, falsified). sc0 L2-local sync
// falsified (R5 fail / R6 fallback). Coords-in-slot (R7) REGRESSED +26%:
// 3 tagged words per poll tripled fabric traffic and tightened the accept
// condition -- reverted to single-word protocol.
// R17: the per-iter wait covers the SLOWEST of 32 publishers, including
// laggards that cannot win. Exact shortcut: each block's published d is
// monotone non-increasing across iterations (D is a running fminf chain, so
// the block max of mins only shrinks). A reader holding a stale slot b can
// bound block b's current value by its last-seen d. ACCEPT the max over
// fresh slots as global winner once every stale slot's bound is STRICTLY
// below the fresh max's d-field. Strictness preserves the exact (d, idx)
// tie-break: any possible tie forces a full wait. Every block reaches the
// identical winner whatever subset it saw fresh (stale blocks provably lose
// in all views). Termination == R0 (all-fresh always accepts).
// Everything else (heaters, 32x64 fps roles, parity banks, 128B slots,
// 4-deep rotating spin, u64 max == np.argmax first-occurrence, poison tag
// 0/0xAAAA never matches) is R0 verbatim.
// Exact numerics: op order sub,mul,mul,add,mul,add,fminf under contract(off).
// ---------------------------------------------------------------------------
#define FPB  32     // fps blocks
#define FBT  64     // active fps threads per block (one wave)
#define FPP  16     // points per thread; FPB*FBT*FPP == NPTS
#define SPAD 16     // u64s per slot (128 B line)
#define HEAT_DONE 0x600DD00Du
#define HEAT_CAP  4096      // outer-loop safety cap (~50ms)

__global__ __launch_bounds__(256) void fps_heat_kernel(const float* __restrict__ xyz,
                                                       float* __restrict__ d_out,
                                                       unsigned long long* __restrict__ slots,
                                                       unsigned int* __restrict__ flag,
                                                       float* __restrict__ hdump)
{
#pragma clang fp contract(off)
    const int t = threadIdx.x;
    const int b = blockIdx.x;

    if (b >= FPB) {
        // ----------------- HEATER: dense FMA, poll flag every ~13us --------
        float a0 = 1.0f + (float)(b * 256 + t) * 1e-6f;
        float a1 = a0 + 0.1f, a2 = a0 + 0.2f, a3 = a0 + 0.3f;
        float a4 = a0 + 0.4f, a5 = a0 + 0.5f, a6 = a0 + 0.6f, a7 = a0 + 0.7f;
        for (int outer = 0; outer < HEAT_CAP; ++outer) {
            #pragma unroll 8
            for (int n = 0; n < 2048; ++n) {
                a0 = fmaf(a0, 0.9999999f, 1e-7f);
                a1 = fmaf(a1, 0.9999999f, 1e-7f);
                a2 = fmaf(a2, 0.9999999f, 1e-7f);
                a3 = fmaf(a3, 0.9999999f, 1e-7f);
                a4 = fmaf(a4, 0.9999999f, 1e-7f);
                a5 = fmaf(a5, 0.9999999f, 1e-7f);
                a6 = fmaf(a6, 0.9999999f, 1e-7f);
                a7 = fmaf(a7, 0.9999999f, 1e-7f);
            }
            if (__hip_atomic_load(flag, __ATOMIC_RELAXED,
                                  __HIP_MEMORY_SCOPE_AGENT) == HEAT_DONE)
                break;
        }
        // never-true guard store keeps the loop from being optimized out
        float s = a0 + a1 + a2 + a3 + a4 + a5 + a6 + a7;
        if (s == 1234.56789f) hdump[(b - FPB) * 256 + t] = s;
        return;
    }

    if (t >= FBT) return;   // fps role: one wave per block

    const int base = b * (FBT * FPP);

    float X[FPP], Y[FPP], Z[FPP], D[FPP];
    #pragma unroll
    for (int k = 0; k < FPP; ++k) {
        const int p = base + k * FBT + t;
        X[k] = xyz[3 * p + 0];
        Y[k] = xyz[3 * p + 1];
        Z[k] = xyz[3 * p + 2];
        D[k] = 1e38f;
    }
    float fx = xyz[0], fy = xyz[1], fz = xyz[2];   // far = 0 at start

    // monotone-bound state for this lane's polled slot (t&31)
    unsigned lastTag = 0u;
    unsigned boundD  = 0xFFFFFFFFu;   // no info yet -> full wait (R0 semantics)

    for (int i = 0; i < NPOINT; ++i) {
        const int par = i & 1;
        const unsigned tag = (unsigned)(i + 1);

        if (b == 0 && t == 0) {   // emit current far point's coords
            d_out[3 * i + 0] = fx;
            d_out[3 * i + 1] = fy;
            d_out[3 * i + 2] = fz;
        }

        // --- distance update (exact np op order) + thread max (4 accs) ---
        float m0 = -1.0f, m1 = -1.0f, m2 = -1.0f, m3 = -1.0f;
        #pragma unroll
        for (int k = 0; k < FPP; k += 4) {
            {   float dx = X[k+0]-fx, dy = Y[k+0]-fy, dz = Z[k+0]-fz;
                float d = ((dx*dx)+(dy*dy))+(dz*dz);
                float Dn = fminf(D[k+0], d); D[k+0] = Dn; m0 = fmaxf(m0, Dn); }
            {   float dx = X[k+1]-fx, dy = Y[k+1]-fy, dz = Z[k+1]-fz;
                float d = ((dx*dx)+(dy*dy))+(dz*dz);
                float Dn = fminf(D[k+1], d); D[k+1] = Dn; m1 = fmaxf(m1, Dn); }
            {   float dx = X[k+2]-fx, dy = Y[k+2]-fy, dz = Z[k+2]-fz;
                float d = ((dx*dx)+(dy*dy))+(dz*dz);
                float Dn = fminf(D[k+2], d); D[k+2] = Dn; m2 = fmaxf(m2, Dn); }
            {   float dx = X[k+3]-fx, dy = Y[k+3]-fy, dz = Z[k+3]-fz;
                float d = ((dx*dx)+(dy*dy))+(dz*dz);
                float Dn = fminf(D[k+3], d); D[k+3] = Dn; m3 = fmaxf(m3, Dn); }
        }
        const float m = fmaxf(fmaxf(m0, m1), fmaxf(m2, m3));

        // --- wave max (butterfly -> all lanes) ---
        float wmax = m;
        #pragma unroll
        for (int mask = 32; mask >= 1; mask >>= 1)
            wmax = fmaxf(wmax, __shfl_xor(wmax, mask, 64));

        // --- block winner index: equality scan + wave min ---
        int cand = 0x7fffffff;
        if (m == wmax) {
            #pragma unroll
            for (int k = FPP - 1; k >= 0; --k)
                if (D[k] == wmax) cand = base + k * FBT + t;  // lowest k wins
        }
        int wcand = cand;
        #pragma unroll
        for (int mask = 32; mask >= 1; mask >>= 1)
            wcand = min(wcand, __shfl_xor(wcand, mask, 64));

        // --- publish (one u64, own 128B line, data+flag in one word) ---
        if (t == 0) {
            const unsigned db  = __float_as_uint(wmax);       // d>=0: order-preserving
            const unsigned inv = 0xFFFFu - (unsigned)wcand;   // bigger = smaller idx
            unsigned long long pk = ((unsigned long long)db << 32)
                                  | ((unsigned long long)inv << 16)
                                  | (unsigned long long)tag;
            __hip_atomic_store(&slots[(size_t)(par * FPB + b) * SPAD], pk,
                               __ATOMIC_RELAXED, __HIP_MEMORY_SCOPE_AGENT);
        }

        // --- 4-deep rotating spin with monotone early-exit -----------------
        // Accept max over FRESH slots once every stale slot's bound is
        // STRICTLY below the fresh max's d-field (exact: ties force wait).
        unsigned long long vwin = 0;
        {
            const unsigned long long* sp =
                &slots[(size_t)(par * FPB + (t & 31)) * SPAD];
#define LD1() __hip_atomic_load(sp, __ATOMIC_RELAXED, __HIP_MEMORY_SCOPE_AGENT)
#define CHK(W)                                                               \
            {                                                                \
                const unsigned tau = (unsigned)((W) & 0xFFFFull);            \
                const bool fr = (tau == tag);                                \
                if (tau > lastTag && tau <= tag) {                           \
                    lastTag = tau;                                           \
                    boundD  = (unsigned)((W) >> 32);                         \
                }                                                            \
                unsigned long long fm = fr ? (W) : 0ull;                     \
                _Pragma("unroll")                                            \
                for (int mk = 32; mk >= 1; mk >>= 1) {                       \
                    unsigned long long o = __shfl_xor(fm, mk, 64);           \
                    if (o > fm) fm = o;                                      \
                }                                                            \
                const bool blocking =                                        \
                    (!fr) && (boundD >= (unsigned)(fm >> 32));               \
                if (!__any((int)blocking)) { vwin = fm; goto accept;         \
                }                                                            \
            }
            unsigned long long w0 = LD1();
            unsigned long long w1 = LD1();
            unsigned long long w2 = LD1();
            unsigned long long w3 = LD1();
            for (;;) {
                CHK(w0); w0 = LD1();
                CHK(w1); w1 = LD1();
                CHK(w2); w2 = LD1();
                CHK(w3); w3 = LD1();
            }
accept:     ;
#undef CHK
#undef LD1
        }

        const int w = __builtin_amdgcn_readfirstlane(
                          (int)(0xFFFFu - (unsigned)((vwin >> 16) & 0xFFFFull)));

        const float* fw = xyz + 3 * w;   // uniform -> scalar loads
        fx = fw[0];
        fy = fw[1];
        fz = fw[2];
    }

    if (b == 0 && t == 0)   // release the heaters
        __hip_atomic_store(flag, HEAT_DONE, __ATOMIC_RELAXED,
                           __HIP_MEMORY_SCOPE_AGENT);
}

// ---------------------------------------------------------------------------
// Kernel B: ball query — exact (d2, idx)-lexicographic 32-smallest per centroid
// ---------------------------------------------------------------------------
#define BT   256
#define BCAP 3072   // in-radius cap (expected worst ~1100 near origin)

__global__ __launch_bounds__(BT) void ballq_kernel(const float* __restrict__ xyz,
                                                   const float* __restrict__ newxyz,
                                                   int* __restrict__ gidx)
{
#pragma clang fp contract(off)
    __shared__ float Ld[BCAP + 128];
    __shared__ int   Li[BCAP + 128];
    __shared__ int   cnt, pcnt;
    __shared__ float cs[3];
    __shared__ float rv[BT / 64];
    __shared__ int   ri[BT / 64], rj[BT / 64];

    const int m = blockIdx.x;
    const int t = threadIdx.x;

    if (t == 0) {
        cnt = 0; pcnt = 0;
        cs[0] = newxyz[3 * m + 0];
        cs[1] = newxyz[3 * m + 1];
        cs[2] = newxyz[3 * m + 2];
    }
    __syncthreads();
    const float cx = cs[0], cy = cs[1], cz = cs[2];

    for (int p = t; p < NPTS; p += BT) {
        float dx = cx - xyz[3 * p + 0];
        float dy = cy - xyz[3 * p + 1];
        float dz = cz - xyz[3 * p + 2];
        float d2 = ((dx * dx) + (dy * dy)) + (dz * dz);
        if (!(d2 > RADIUS2)) {                    // in radius (keeps d2 == r^2)
            int pos = atomicAdd(&cnt, 1);
            if (pos < BCAP) { Ld[pos] = d2; Li[pos] = p; }
        } else if (p < 128) {                     // padding candidates (masked 1e9)
            int pos = atomicAdd(&pcnt, 1);
            Ld[BCAP + pos] = 1e9f;
            Li[BCAP + pos] = p;
        }
    }
    __syncthreads();

    const int L = (cnt < BCAP) ? cnt : BCAP;
    const int P = pcnt;
    if (t < P) {  // compact pads to follow the in-radius list
        float d = Ld[BCAP + t];
        int   x = Li[BCAP + t];
        Ld[L + t] = d;
        Li[L + t] = x;
    }
    __syncthreads();
    const int M = L + P;

    for (int r = 0; r < NSAMPLE; ++r) {
        float bd = 3e38f;
        int   bi = 0x7fffffff;
        int   bj = 0;
        for (int j = t; j < M; j += BT) {
            float d = Ld[j];
            int   x = Li[j];
            if (d < bd || (d == bd && x < bi)) { bd = d; bi = x; bj = j; }
        }
        #pragma unroll
        for (int mask = 32; mask >= 1; mask >>= 1) {
            float ov = __shfl_xor(bd, mask, 64);
            int   oi = __shfl_xor(bi, mask, 64);
            int   oj = __shfl_xor(bj, mask, 64);
            if (ov < bd || (ov == bd && oi < bi)) { bd = ov; bi = oi; bj = oj; }
        }
        if ((t & 63) == 0) { rv[t >> 6] = bd; ri[t >> 6] = bi; rj[t >> 6] = bj; }
        __syncthreads();
        if (t == 0) {
            float v0 = rv[0]; int i0 = ri[0]; int j0 = rj[0];
            for (int w = 1; w < BT / 64; ++w) {
                if (rv[w] < v0 || (rv[w] == v0 && ri[w] < i0)) { v0 = rv[w]; i0 = ri[w]; j0 = rj[w]; }
            }
            gidx[m * NSAMPLE + r] = i0;
            Ld[j0] = 3e38f;   // remove from candidate set
        }
        __syncthreads();
    }
}

// ---------------------------------------------------------------------------
// Kernel C: gather -> MLP(67->64->128, exact GELU) -> maxpool, 1 block/centroid
// ---------------------------------------------------------------------------
__global__ __launch_bounds__(256) void mlp_kernel(const float* __restrict__ xyz,
                                                  const float* __restrict__ feat,
                                                  const float* __restrict__ W1,
                                                  const float* __restrict__ b1,
                                                  const float* __restrict__ W2,
                                                  const float* __restrict__ b2,
                                                  const float* __restrict__ newxyz,
                                                  const int* __restrict__ gidx,
                                                  float* __restrict__ out_pooled)
{
    __shared__ float W1s[D0 * H1DIM];            // 17152 B
    __shared__ float W2s[H1DIM * H2DIM];         // 32768 B
    __shared__ float b1s[H1DIM];
    __shared__ float b2s[H2DIM];
    __shared__ float Xs[NSAMPLE][D0 + 1];        // 68 stride
    __shared__ float H1s[NSAMPLE][H1DIM + 4];    // 68 stride
    __shared__ float H2s[NSAMPLE][H2DIM + 4];    // 132 stride
    __shared__ int   idxs[NSAMPLE];
    __shared__ float cs[3];

    const int m = blockIdx.x;
    const int t = threadIdx.x;

    for (int i = t; i < D0 * H1DIM; i += 256) W1s[i] = W1[i];
    for (int i = t; i < H1DIM * H2DIM; i += 256) W2s[i] = W2[i];
    if (t < H1DIM) b1s[t] = b1[t];
    if (t < H2DIM) b2s[t] = b2[t];
    if (t < NSAMPLE) idxs[t] = gidx[m * NSAMPLE + t];
    if (t < 3) cs[t] = newxyz[3 * m + t];
    __syncthreads();

    const int s  = t >> 3;   // sample 0..31
    const int u  = t & 7;    // sub-worker 0..7

    {   // gather: g_xyz (relative) + feat
        const int id = idxs[s];
        const float4* f4 = (const float4*)(feat + (size_t)id * D_IN);
        float4 a = f4[u * 2 + 0];
        float4 b = f4[u * 2 + 1];
        Xs[s][3 + u * 8 + 0] = a.x; Xs[s][3 + u * 8 + 1] = a.y;
        Xs[s][3 + u * 8 + 2] = a.z; Xs[s][3 + u * 8 + 3] = a.w;
        Xs[s][3 + u * 8 + 4] = b.x; Xs[s][3 + u * 8 + 5] = b.y;
        Xs[s][3 + u * 8 + 6] = b.z; Xs[s][3 + u * 8 + 7] = b.w;
        if (u == 0) {
            Xs[s][0] = xyz[3 * id + 0] - cs[0];
            Xs[s][1] = xyz[3 * id + 1] - cs[1];
            Xs[s][2] = xyz[3 * id + 2] - cs[2];
        }
    }
    __syncthreads();

    // layer 1: each thread computes 8 of 64 outputs for its sample
    {
        float acc[8];
        #pragma unroll
        for (int v = 0; v < 8; ++v) acc[v] = b1s[u * 8 + v];
        for (int k = 0; k < D0; ++k) {
            float xk = Xs[s][k];
            float4 wa = *(const float4*)&W1s[k * H1DIM + u * 8 + 0];
            float4 wb = *(const float4*)&W1s[k * H1DIM + u * 8 + 4];
            acc[0] = fmaf(xk, wa.x, acc[0]); acc[1] = fmaf(xk, wa.y, acc[1]);
            acc[2] = fmaf(xk, wa.z, acc[2]); acc[3] = fmaf(xk, wa.w, acc[3]);
            acc[4] = fmaf(xk, wb.x, acc[4]); acc[5] = fmaf(xk, wb.y, acc[5]);
            acc[6] = fmaf(xk, wb.z, acc[6]); acc[7] = fmaf(xk, wb.w, acc[7]);
        }
        #pragma unroll
        for (int v = 0; v < 8; ++v) {
            float a = acc[v];
            H1s[s][u * 8 + v] = 0.5f * a * (1.0f + erff(a * 0.70710678118654752f));
        }
    }
    __syncthreads();

    // layer 2: each thread computes 16 of 128 outputs for its sample
    {
        float acc[16];
        #pragma unroll
        for (int v = 0; v < 16; ++v) acc[v] = b2s[u * 16 + v];
        for (int k = 0; k < H1DIM; ++k) {
            float hk = H1s[s][k];
            #pragma unroll
            for (int q = 0; q < 4; ++q) {
                float4 w = *(const float4*)&W2s[k * H2DIM + u * 16 + q * 4];
                acc[q * 4 + 0] = fmaf(hk, w.x, acc[q * 4 + 0]);
                acc[q * 4 + 1] = fmaf(hk, w.y, acc[q * 4 + 1]);
                acc[q * 4 + 2] = fmaf(hk, w.z, acc[q * 4 + 2]);
                acc[q * 4 + 3] = fmaf(hk, w.w, acc[q * 4 + 3]);
            }
        }
        #pragma unroll
        for (int v = 0; v < 16; ++v) {
            float a = acc[v];
            H2s[s][u * 16 + v] = 0.5f * a * (1.0f + erff(a * 0.70710678118654752f));
        }
    }
    __syncthreads();

    // maxpool over 32 samples
    if (t < H2DIM) {
        float mx = H2s[0][t];
        #pragma unroll 4
        for (int ss = 1; ss < NSAMPLE; ++ss) mx = fmaxf(mx, H2s[ss][t]);
        out_pooled[(size_t)m * H2DIM + t] = mx;
    }
}

// ---------------------------------------------------------------------------
extern "C" void kernel_launch(void* const* d_in, const int* in_sizes, int n_in,
                              void* d_out, int out_size, void* d_ws, size_t ws_size,
                              hipStream_t stream) {
    const float* xyz  = (const float*)d_in[0];
    const float* feat = (const float*)d_in[1];
    const float* W1   = (const float*)d_in[2];
    const float* b1   = (const float*)d_in[3];
    const float* W2   = (const float*)d_in[4];
    const float* b2   = (const float*)d_in[5];
    float* out = (float*)d_out;
    int*   gidx = (int*)d_ws;                               // 256 KiB
    unsigned int* flag = (unsigned int*)((char*)d_ws + NPOINT * NSAMPLE * 4);
    // ws poison 0xAAAAAAAA != HEAT_DONE -> heater armed each call.

    // Cross-block slots + heater guard dump: pooled-output region (unused
    // until mlp overwrites). Slots: 2 banks x 32 x 128B = 8KB; dump at +16KB.
    unsigned long long* slots = (unsigned long long*)(out + 3 * NPOINT);
    float* hdump = out + 3 * NPOINT + 4096;

    fps_heat_kernel<<<256, 256, 0, stream>>>(xyz, out, slots, flag, hdump);
    ballq_kernel<<<NPOINT, BT, 0, stream>>>(xyz, out, gidx);
    mlp_kernel<<<NPOINT, 256, 0, stream>>>(xyz, feat, W1, b1, W2, b2,
                                           out, gidx, out + 3 * NPOINT);
}